// Round 1
// baseline (790.487 us; speedup 1.0000x reference)
//
#include <hip/hip_runtime.h>

// EdgeGAT on MI355X — round 1: correct fp32 baseline.
//
// Pipeline:
//   k0: wsum[j]   = sum_k W_fij[k,j]                      (256 outputs)
//   k1: fused[n,0:256]   = nfeats@W_ni + bias             (one 50000x256x768 SGEMM)
//       fused[n,256:512] = nfeats@W_nj
//       fused[n,512:768] = nfeats@W_node
//   k2: per edge: e[h] = sum_o attn[h,o]*leaky(f_ni'[src]+f_nj[dst]+r*wsum)
//       ee = exp(e)  (segment-max dropped: exp(e)/sum exp(e) is identical)
//       atomicAdd denom[dst,h]
//   k3: per edge: out[dst,o] += 0.25 * sum_h (ee/denom[dst,h]) * h_src[src,h,o]
//   k4: relu in place on out

#define BM 64
#define BN 64
#define BK 16

__global__ __launch_bounds__(256) void wsum_kernel(const float* __restrict__ Wfij,
                                                   float* __restrict__ wsum) {
    int j = threadIdx.x;  // 256 threads, one block
    float s = 0.f;
#pragma unroll
    for (int k = 0; k < 32; ++k) s += Wfij[k * 256 + j];
    wsum[j] = s;
}

// C[N,768] = A[N,256] @ [W_ni | W_nj | W_node], bias folded into first segment.
__global__ __launch_bounds__(256) void gemm_fused(
    const float* __restrict__ A, const float* __restrict__ Wni,
    const float* __restrict__ Wnj, const float* __restrict__ Wnode,
    const float* __restrict__ bias, float* __restrict__ out, int N) {
    __shared__ float As[BK][BM + 4];  // +4 pad: keeps 16B alignment, kills store conflicts
    __shared__ float Bs[BK][BN];

    const int bx = blockIdx.x;        // row block
    const int by = blockIdx.y;        // col block 0..11
    const int seg = by >> 2;          // 0:ni 1:nj 2:node
    const float* B = (seg == 0) ? Wni : (seg == 1) ? Wnj : Wnode;
    const int jbase = (by & 3) * BN;  // column base within segment

    const int tid = threadIdx.x;
    const int tm = tid >> 4;          // 0..15
    const int tn = tid & 15;          // 0..15
    const int row0 = bx * BM;

    // A loader: thread -> (row, 4 consecutive k)
    const int arow = tid >> 2;              // 0..63
    const int ak = (tid & 3) * 4;           // 0,4,8,12
    // B loader: thread -> (k row, 4 consecutive j)
    const int brow = tid >> 4;              // 0..15
    const int bj = (tid & 15) * 4;          // 0..60

    float acc[4][4] = {};

    for (int k0 = 0; k0 < 256; k0 += BK) {
        float4 av = make_float4(0.f, 0.f, 0.f, 0.f);
        int grow = row0 + arow;
        if (grow < N) av = *(const float4*)(A + (size_t)grow * 256 + k0 + ak);
        As[ak + 0][arow] = av.x;
        As[ak + 1][arow] = av.y;
        As[ak + 2][arow] = av.z;
        As[ak + 3][arow] = av.w;

        float4 bv = *(const float4*)(B + (size_t)(k0 + brow) * 256 + jbase + bj);
        *(float4*)&Bs[brow][bj] = bv;
        __syncthreads();

#pragma unroll
        for (int kk = 0; kk < BK; ++kk) {
            float4 a4 = *(const float4*)&As[kk][tm * 4];
            float4 b4 = *(const float4*)&Bs[kk][tn * 4];
            float a[4] = {a4.x, a4.y, a4.z, a4.w};
            float b[4] = {b4.x, b4.y, b4.z, b4.w};
#pragma unroll
            for (int i = 0; i < 4; ++i)
#pragma unroll
                for (int j = 0; j < 4; ++j) acc[i][j] += a[i] * b[j];
        }
        __syncthreads();
    }

#pragma unroll
    for (int i = 0; i < 4; ++i) {
        int r = row0 + tm * 4 + i;
        if (r >= N) continue;
#pragma unroll
        for (int j = 0; j < 4; ++j) {
            int c = jbase + tn * 4 + j;  // within-segment column
            float v = acc[i][j];
            if (seg == 0) v += bias[c];
            out[(size_t)r * 768 + seg * 256 + c] = v;
        }
    }
}

// One wave per edge: leaky-relu'd logits dotted with attn, exp, denom atomics.
__global__ __launch_bounds__(256) void edge_logits(
    const float* __restrict__ fused, const float* __restrict__ reward,
    const int* __restrict__ src, const int* __restrict__ dst,
    const float* __restrict__ wsum, const float* __restrict__ attn,
    float* __restrict__ ee, float* __restrict__ denom, int E) {
    int wid = (int)((blockIdx.x * (size_t)blockDim.x + threadIdx.x) >> 6);
    int lane = threadIdx.x & 63;
    if (wid >= E) return;

    int s = src[wid], d = dst[wid];
    float r = reward[wid];
    const float* fni = fused + (size_t)s * 768;        // bias already folded in
    const float* fnj = fused + (size_t)d * 768 + 256;

    float acc[4];
#pragma unroll
    for (int h = 0; h < 4; ++h) {
        int j = h * 64 + lane;
        float x = fni[j] + fnj[j] + r * wsum[j];
        x = x > 0.f ? x : 0.2f * x;
        acc[h] = attn[j] * x;
    }
#pragma unroll
    for (int off = 32; off; off >>= 1) {
#pragma unroll
        for (int h = 0; h < 4; ++h) acc[h] += __shfl_xor(acc[h], off, 64);
    }
    if (lane < 4) {
        float sv = (lane == 0) ? acc[0] : (lane == 1) ? acc[1] : (lane == 2) ? acc[2] : acc[3];
        float v = __expf(sv);
        ee[(size_t)wid * 4 + lane] = v;
        atomicAdd(&denom[(size_t)d * 4 + lane], v);
    }
}

// One wave per edge: head-weighted gather of h_src, head-mean folded in, scatter-add.
__global__ __launch_bounds__(256) void aggregate(
    const float* __restrict__ fused, const float* __restrict__ ee,
    const float* __restrict__ denom, const int* __restrict__ src,
    const int* __restrict__ dst, float* __restrict__ out, int E) {
    int wid = (int)((blockIdx.x * (size_t)blockDim.x + threadIdx.x) >> 6);
    int lane = threadIdx.x & 63;
    if (wid >= E) return;

    int s = src[wid], d = dst[wid];
    float4 e4 = *(const float4*)(ee + (size_t)wid * 4);
    float4 dn = *(const float4*)(denom + (size_t)d * 4);
    float c0 = __fdividef(e4.x, dn.x);
    float c1 = __fdividef(e4.y, dn.y);
    float c2 = __fdividef(e4.z, dn.z);
    float c3 = __fdividef(e4.w, dn.w);

    const float* hs = fused + (size_t)s * 768 + 512;
    float val = 0.25f * (c0 * hs[lane] + c1 * hs[64 + lane] +
                         c2 * hs[128 + lane] + c3 * hs[192 + lane]);
    atomicAdd(out + (size_t)d * 64 + lane, val);
}

__global__ __launch_bounds__(256) void relu_kernel(float* __restrict__ out, int n) {
    int i = blockIdx.x * 256 + threadIdx.x;
    if (i < n) out[i] = fmaxf(out[i], 0.f);
}

extern "C" void kernel_launch(void* const* d_in, const int* in_sizes, int n_in,
                              void* d_out, int out_size, void* d_ws, size_t ws_size,
                              hipStream_t stream) {
    const float* nfeats = (const float*)d_in[0];
    const float* reward = (const float*)d_in[1];
    const int* src = (const int*)d_in[2];
    const int* dst = (const int*)d_in[3];
    const float* Wni = (const float*)d_in[4];
    const float* Wnj = (const float*)d_in[5];
    const float* Wfij = (const float*)d_in[6];
    const float* Wnode = (const float*)d_in[7];
    const float* bias = (const float*)d_in[8];
    const float* attn = (const float*)d_in[9];
    float* out = (float*)d_out;

    const int N = in_sizes[0] / 256;
    const int E = in_sizes[1];

    // workspace layout (fp32): fused[N,768] | ee[E,4] | denom[N,4] | wsum[256]
    float* fused = (float*)d_ws;
    float* ee = fused + (size_t)N * 768;
    float* denom = ee + (size_t)E * 4;
    float* wsum = denom + (size_t)N * 4;

    hipMemsetAsync(denom, 0, (size_t)N * 4 * sizeof(float), stream);
    hipMemsetAsync(d_out, 0, (size_t)out_size * sizeof(float), stream);

    wsum_kernel<<<1, 256, 0, stream>>>(Wfij, wsum);

    dim3 g1((N + BM - 1) / BM, 12);
    gemm_fused<<<g1, 256, 0, stream>>>(nfeats, Wni, Wnj, Wnode, bias, fused, N);

    int blocks_e = (E + 3) / 4;  // 4 waves (edges) per 256-thread block
    edge_logits<<<blocks_e, 256, 0, stream>>>(fused, reward, src, dst, wsum, attn,
                                              ee, denom, E);
    aggregate<<<blocks_e, 256, 0, stream>>>(fused, ee, denom, src, dst, out, E);

    int total = N * 64;
    relu_kernel<<<(total + 255) / 256, 256, 0, stream>>>(out, total);
}

// Round 2
// 580.068 us; speedup vs baseline: 1.3627x; 1.3627x over previous
//
#include <hip/hip_runtime.h>

// EdgeGAT on MI355X — round 2: bf16 MFMA GEMM + bf16 attention features.
//
// Pipeline:
//   c0: cast nfeats fp32 -> bf16 (Abf)
//   c1: concat+cast [W_ni|W_nj|W_node] -> Bcat bf16 [256][768]
//   k0: wsum[j] = sum_k W_fij[k,j]
//   k1: MFMA GEMM: [N,256]x[256,768]; cols 0..511 (+bias on 0..255) -> fatt bf16,
//       cols 512..767 -> hsrc fp32
//   k2: edge logits (gather fatt bf16), exp, denom atomics
//   k3: aggregate (gather hsrc fp32), atomic scatter to out
//   k4: relu

typedef unsigned short ushort_t;
typedef __attribute__((ext_vector_type(8))) unsigned short ushort8v;
typedef __attribute__((ext_vector_type(8))) short frag_t;     // 8 bf16 (4 VGPRs)
typedef __attribute__((ext_vector_type(4))) float f32x4;

__device__ __forceinline__ ushort_t f2bf(float f) {
    unsigned u = __float_as_uint(f);
    unsigned r = u + 0x7fffu + ((u >> 16) & 1u);   // round-to-nearest-even
    return (ushort_t)(r >> 16);
}
__device__ __forceinline__ float bf2f(ushort_t v) {
    return __uint_as_float(((unsigned)v) << 16);
}

// ---- cast kernels -----------------------------------------------------------

__global__ __launch_bounds__(256) void cast_nfeats(const float* __restrict__ in,
                                                   ushort_t* __restrict__ out, int total4) {
    int i = blockIdx.x * 256 + threadIdx.x;
    if (i >= total4) return;
    float4 v = *(const float4*)(in + (size_t)i * 4);
    ushort4 o;
    o.x = f2bf(v.x); o.y = f2bf(v.y); o.z = f2bf(v.z); o.w = f2bf(v.w);
    *(ushort4*)(out + (size_t)i * 4) = o;
}

// grid=(256), block=(768): Bcat[k][j], j<256: Wni, j<512: Wnj, else Wnode
__global__ __launch_bounds__(768) void build_bcat(const float* __restrict__ Wni,
                                                  const float* __restrict__ Wnj,
                                                  const float* __restrict__ Wnode,
                                                  ushort_t* __restrict__ Bcat) {
    int k = blockIdx.x;
    int j = threadIdx.x;
    int seg = j >> 8;
    const float* W = (seg == 0) ? Wni : (seg == 1) ? Wnj : Wnode;
    Bcat[(size_t)k * 768 + j] = f2bf(W[(size_t)k * 256 + (j & 255)]);
}

__global__ __launch_bounds__(256) void wsum_kernel(const float* __restrict__ Wfij,
                                                   float* __restrict__ wsum) {
    int j = threadIdx.x;
    float s = 0.f;
#pragma unroll
    for (int k = 0; k < 32; ++k) s += Wfij[k * 256 + j];
    wsum[j] = s;
}

// ---- MFMA GEMM --------------------------------------------------------------
// Block tile 128x64, BK=32, 4 waves as 2x2; each wave: 4 m-tiles x 2 n-tiles
// of 16x16x32 bf16 MFMA. A frag layout: A[m=lane&15][k=quad*8+j];
// B frag layout: B[k=quad*8+j][n=lane&15] via Bs stored transposed [n][k].
// C/D layout: col=lane&15, row=quad*4+reg (verified m89).

__global__ __launch_bounds__(256) void gemm_mfma(
    const ushort_t* __restrict__ A, const ushort_t* __restrict__ B,
    const float* __restrict__ bias, ushort_t* __restrict__ fatt,
    float* __restrict__ hsrc, int N) {
    __shared__ ushort_t As[128][40];   // row stride 80B (16B-aligned, bank-uniform)
    __shared__ ushort_t Bs[64][40];

    const int tid = threadIdx.x;
    const int wave = tid >> 6, lane = tid & 63;
    const int quad = lane >> 4, l16 = lane & 15;
    const int wrow = wave & 1, wcol = wave >> 1;
    const int row0 = blockIdx.x * 128;
    const int col0 = blockIdx.y * 64;          // 0..704

    // A staging map: thread -> (row=tid>>1, kseg=(tid&1)*16), two ushort8 loads
    const int ar = tid >> 1;
    const int ak = (tid & 1) * 16;
    // B staging map: thread -> (k=tid>>3, n0=(tid&7)*8), one ushort8 load
    const int bk = tid >> 3;
    const int bn = (tid & 7) * 8;

    f32x4 acc[4][2] = {};

    for (int k0 = 0; k0 < 256; k0 += 32) {
        if (k0) __syncthreads();
        // stage A (128x32)
        {
            int grow = row0 + ar;
            ushort8v v0 = {}, v1 = {};
            if (grow < N) {
                const ushort_t* p = A + (size_t)grow * 256 + k0 + ak;
                v0 = *(const ushort8v*)p;
                v1 = *(const ushort8v*)(p + 8);
            }
            *(ushort8v*)&As[ar][ak] = v0;
            *(ushort8v*)&As[ar][ak + 8] = v1;
        }
        // stage B (32k x 64n) transposed -> Bs[n][k]
        {
            ushort8v v = *(const ushort8v*)(B + (size_t)(k0 + bk) * 768 + col0 + bn);
#pragma unroll
            for (int j = 0; j < 8; ++j) Bs[bn + j][bk] = v[j];
        }
        __syncthreads();

        frag_t af[4], bfr[2];
#pragma unroll
        for (int i = 0; i < 4; ++i)
            af[i] = *(const frag_t*)&As[wrow * 64 + i * 16 + l16][quad * 8];
#pragma unroll
        for (int j = 0; j < 2; ++j)
            bfr[j] = *(const frag_t*)&Bs[wcol * 32 + j * 16 + l16][quad * 8];

#pragma unroll
        for (int i = 0; i < 4; ++i)
#pragma unroll
            for (int j = 0; j < 2; ++j)
                acc[i][j] = __builtin_amdgcn_mfma_f32_16x16x32_bf16(af[i], bfr[j], acc[i][j], 0, 0, 0);
    }

    // epilogue: col range for this block is [col0, col0+64) — single segment
#pragma unroll
    for (int i = 0; i < 4; ++i) {
#pragma unroll
        for (int j = 0; j < 2; ++j) {
#pragma unroll
            for (int r = 0; r < 4; ++r) {
                int row = row0 + wrow * 64 + i * 16 + quad * 4 + r;
                if (row >= N) continue;
                int col = col0 + wcol * 32 + j * 16 + l16;
                float v = acc[i][j][r];
                if (col < 256) v += bias[col];
                if (col < 512)
                    fatt[(size_t)row * 512 + col] = f2bf(v);
                else
                    hsrc[(size_t)row * 256 + (col - 512)] = v;
            }
        }
    }
}

// ---- edge kernels -----------------------------------------------------------

// One wave per edge. lane covers j = lane*4..lane*4+3 (all in head lane>>4).
__global__ __launch_bounds__(256) void edge_logits(
    const ushort_t* __restrict__ fatt, const float* __restrict__ reward,
    const int* __restrict__ src, const int* __restrict__ dst,
    const float* __restrict__ wsum, const float* __restrict__ attn,
    float* __restrict__ ee, float* __restrict__ denom, int E) {
    int wid = (int)((blockIdx.x * (size_t)blockDim.x + threadIdx.x) >> 6);
    int lane = threadIdx.x & 63;
    if (wid >= E) return;

    int s = src[wid], d = dst[wid];
    float r = reward[wid];
    int j0 = lane * 4;

    ushort4 ni = *(const ushort4*)(fatt + (size_t)s * 512 + j0);
    ushort4 nj = *(const ushort4*)(fatt + (size_t)d * 512 + 256 + j0);
    float4 ws = *(const float4*)(wsum + j0);
    float4 at = *(const float4*)(attn + j0);

    float acc;
    {
        float x0 = bf2f(ni.x) + bf2f(nj.x) + r * ws.x;
        float x1 = bf2f(ni.y) + bf2f(nj.y) + r * ws.y;
        float x2 = bf2f(ni.z) + bf2f(nj.z) + r * ws.z;
        float x3 = bf2f(ni.w) + bf2f(nj.w) + r * ws.w;
        x0 = x0 > 0.f ? x0 : 0.2f * x0;
        x1 = x1 > 0.f ? x1 : 0.2f * x1;
        x2 = x2 > 0.f ? x2 : 0.2f * x2;
        x3 = x3 > 0.f ? x3 : 0.2f * x3;
        acc = at.x * x0 + at.y * x1 + at.z * x2 + at.w * x3;
    }
#pragma unroll
    for (int off = 8; off; off >>= 1) acc += __shfl_xor(acc, off, 64);

    if ((lane & 15) == 0) {
        int h = lane >> 4;
        float v = __expf(acc);
        ee[(size_t)wid * 4 + h] = v;
        atomicAdd(&denom[(size_t)d * 4 + h], v);
    }
}

// One wave per edge: lane = o, 4 scattered fp32 gathers from hsrc, 1 atomic.
__global__ __launch_bounds__(256) void aggregate(
    const float* __restrict__ hsrc, const float* __restrict__ ee,
    const float* __restrict__ denom, const int* __restrict__ src,
    const int* __restrict__ dst, float* __restrict__ out, int E) {
    int wid = (int)((blockIdx.x * (size_t)blockDim.x + threadIdx.x) >> 6);
    int lane = threadIdx.x & 63;
    if (wid >= E) return;

    int s = src[wid], d = dst[wid];
    float4 e4 = *(const float4*)(ee + (size_t)wid * 4);
    float4 dn = *(const float4*)(denom + (size_t)d * 4);
    float c0 = __fdividef(e4.x, dn.x);
    float c1 = __fdividef(e4.y, dn.y);
    float c2 = __fdividef(e4.z, dn.z);
    float c3 = __fdividef(e4.w, dn.w);

    const float* hs = hsrc + (size_t)s * 256;
    float val = 0.25f * (c0 * hs[lane] + c1 * hs[64 + lane] +
                         c2 * hs[128 + lane] + c3 * hs[192 + lane]);
    atomicAdd(out + (size_t)d * 64 + lane, val);
}

__global__ __launch_bounds__(256) void relu_kernel(float* __restrict__ out, int n) {
    int i = blockIdx.x * 256 + threadIdx.x;
    if (i < n) out[i] = fmaxf(out[i], 0.f);
}

// ---- launch -----------------------------------------------------------------

extern "C" void kernel_launch(void* const* d_in, const int* in_sizes, int n_in,
                              void* d_out, int out_size, void* d_ws, size_t ws_size,
                              hipStream_t stream) {
    const float* nfeats = (const float*)d_in[0];
    const float* reward = (const float*)d_in[1];
    const int* src = (const int*)d_in[2];
    const int* dst = (const int*)d_in[3];
    const float* Wni = (const float*)d_in[4];
    const float* Wnj = (const float*)d_in[5];
    const float* Wfij = (const float*)d_in[6];
    const float* Wnode = (const float*)d_in[7];
    const float* bias = (const float*)d_in[8];
    const float* attn = (const float*)d_in[9];
    float* out = (float*)d_out;

    const int N = in_sizes[0] / 256;
    const int E = in_sizes[1];

    // workspace: fp32 first, then bf16 arrays (all 16B aligned by construction)
    float* hsrc = (float*)d_ws;                        // N*256 f32
    float* ee = hsrc + (size_t)N * 256;                // E*4 f32
    float* denom = ee + (size_t)E * 4;                 // N*4 f32
    float* wsum = denom + (size_t)N * 4;               // 256 f32
    ushort_t* fatt = (ushort_t*)(wsum + 256);          // N*512 bf16
    ushort_t* Abf = fatt + (size_t)N * 512;            // N*256 bf16
    ushort_t* Bcat = Abf + (size_t)N * 256;            // 256*768 bf16

    hipMemsetAsync(denom, 0, (size_t)N * 4 * sizeof(float), stream);
    hipMemsetAsync(d_out, 0, (size_t)out_size * sizeof(float), stream);

    int total4 = N * 64;  // N*256/4
    cast_nfeats<<<(total4 + 255) / 256, 256, 0, stream>>>(nfeats, Abf, total4);
    build_bcat<<<256, 768, 0, stream>>>(Wni, Wnj, Wnode, Bcat);
    wsum_kernel<<<1, 256, 0, stream>>>(Wfij, wsum);

    dim3 g1((N + 127) / 128, 12);
    gemm_mfma<<<g1, 256, 0, stream>>>(Abf, Bcat, bias, fatt, hsrc, N);

    int blocks_e = (E + 3) / 4;
    edge_logits<<<blocks_e, 256, 0, stream>>>(fatt, reward, src, dst, wsum, attn,
                                              ee, denom, E);
    aggregate<<<blocks_e, 256, 0, stream>>>(hsrc, ee, denom, src, dst, out, E);

    int total = N * 64;
    relu_kernel<<<(total + 255) / 256, 256, 0, stream>>>(out, total);
}

// Round 3
// 487.382 us; speedup vs baseline: 1.6219x; 1.1902x over previous
//
#include <hip/hip_runtime.h>

// EdgeGAT on MI355X — round 3: CSR (sort-by-dst) fused edge phase.
//
// Pipeline:
//   c0: cast nfeats fp32 -> bf16 (Abf)
//   c1: concat+cast [W_ni|W_nj|W_node] -> Bcat bf16 [256][768]
//   k0: wsum[j] = sum_k W_fij[k,j]
//   k1: MFMA GEMM: [N,256]x[256,768]; cols 0..511 (+bias) -> fatt bf16,
//       cols 512..767 -> hsb bf16
//   s0-s4: counting sort of edges by dst -> rowptr/esrc/erew
//   k2: node_fused — per dst node (1 wave): pass1 logits+exp+denom (register
//       reduction, f_nj loaded once), pass2 weighted gather of hsb, coalesced
//       out write with 0.25*mean + relu folded in. No atomics on out/denom.

typedef unsigned short ushort_t;
typedef __attribute__((ext_vector_type(8))) unsigned short ushort8v;
typedef __attribute__((ext_vector_type(8))) short frag_t;     // 8 bf16 (4 VGPRs)
typedef __attribute__((ext_vector_type(4))) float f32x4;

__device__ __forceinline__ ushort_t f2bf(float f) {
    unsigned u = __float_as_uint(f);
    unsigned r = u + 0x7fffu + ((u >> 16) & 1u);   // round-to-nearest-even
    return (ushort_t)(r >> 16);
}
__device__ __forceinline__ float bf2f(ushort_t v) {
    return __uint_as_float(((unsigned)v) << 16);
}

// ---- cast kernels -----------------------------------------------------------

__global__ __launch_bounds__(256) void cast_nfeats(const float* __restrict__ in,
                                                   ushort_t* __restrict__ out, int total4) {
    int i = blockIdx.x * 256 + threadIdx.x;
    if (i >= total4) return;
    float4 v = *(const float4*)(in + (size_t)i * 4);
    ushort4 o;
    o.x = f2bf(v.x); o.y = f2bf(v.y); o.z = f2bf(v.z); o.w = f2bf(v.w);
    *(ushort4*)(out + (size_t)i * 4) = o;
}

__global__ __launch_bounds__(768) void build_bcat(const float* __restrict__ Wni,
                                                  const float* __restrict__ Wnj,
                                                  const float* __restrict__ Wnode,
                                                  ushort_t* __restrict__ Bcat) {
    int k = blockIdx.x;
    int j = threadIdx.x;
    int seg = j >> 8;
    const float* W = (seg == 0) ? Wni : (seg == 1) ? Wnj : Wnode;
    Bcat[(size_t)k * 768 + j] = f2bf(W[(size_t)k * 256 + (j & 255)]);
}

__global__ __launch_bounds__(256) void wsum_kernel(const float* __restrict__ Wfij,
                                                   float* __restrict__ wsum) {
    int j = threadIdx.x;
    float s = 0.f;
#pragma unroll
    for (int k = 0; k < 32; ++k) s += Wfij[k * 256 + j];
    wsum[j] = s;
}

// ---- MFMA GEMM --------------------------------------------------------------

__global__ __launch_bounds__(256) void gemm_mfma(
    const ushort_t* __restrict__ A, const ushort_t* __restrict__ B,
    const float* __restrict__ bias, ushort_t* __restrict__ fatt,
    ushort_t* __restrict__ hsb, int N) {
    __shared__ ushort_t As[128][40];
    __shared__ ushort_t Bs[64][40];

    const int tid = threadIdx.x;
    const int wave = tid >> 6, lane = tid & 63;
    const int quad = lane >> 4, l16 = lane & 15;
    const int wrow = wave & 1, wcol = wave >> 1;
    const int row0 = blockIdx.x * 128;
    const int col0 = blockIdx.y * 64;

    const int ar = tid >> 1;
    const int ak = (tid & 1) * 16;
    const int bk = tid >> 3;
    const int bn = (tid & 7) * 8;

    f32x4 acc[4][2] = {};

    for (int k0 = 0; k0 < 256; k0 += 32) {
        if (k0) __syncthreads();
        {
            int grow = row0 + ar;
            ushort8v v0 = {}, v1 = {};
            if (grow < N) {
                const ushort_t* p = A + (size_t)grow * 256 + k0 + ak;
                v0 = *(const ushort8v*)p;
                v1 = *(const ushort8v*)(p + 8);
            }
            *(ushort8v*)&As[ar][ak] = v0;
            *(ushort8v*)&As[ar][ak + 8] = v1;
        }
        {
            ushort8v v = *(const ushort8v*)(B + (size_t)(k0 + bk) * 768 + col0 + bn);
#pragma unroll
            for (int j = 0; j < 8; ++j) Bs[bn + j][bk] = v[j];
        }
        __syncthreads();

        frag_t af[4], bfr[2];
#pragma unroll
        for (int i = 0; i < 4; ++i)
            af[i] = *(const frag_t*)&As[wrow * 64 + i * 16 + l16][quad * 8];
#pragma unroll
        for (int j = 0; j < 2; ++j)
            bfr[j] = *(const frag_t*)&Bs[wcol * 32 + j * 16 + l16][quad * 8];

#pragma unroll
        for (int i = 0; i < 4; ++i)
#pragma unroll
            for (int j = 0; j < 2; ++j)
                acc[i][j] = __builtin_amdgcn_mfma_f32_16x16x32_bf16(af[i], bfr[j], acc[i][j], 0, 0, 0);
    }

#pragma unroll
    for (int i = 0; i < 4; ++i) {
#pragma unroll
        for (int j = 0; j < 2; ++j) {
#pragma unroll
            for (int r = 0; r < 4; ++r) {
                int row = row0 + wrow * 64 + i * 16 + quad * 4 + r;
                if (row >= N) continue;
                int col = col0 + wcol * 32 + j * 16 + l16;
                float v = acc[i][j][r];
                if (col < 256) v += bias[col];
                if (col < 512)
                    fatt[(size_t)row * 512 + col] = f2bf(v);
                else
                    hsb[(size_t)row * 256 + (col - 512)] = f2bf(v);
            }
        }
    }
}

// ---- counting sort by dst ---------------------------------------------------

__global__ __launch_bounds__(256) void count_kernel(const int* __restrict__ dst,
                                                    int* __restrict__ counts, int E) {
    int i = blockIdx.x * 256 + threadIdx.x;
    if (i < E) atomicAdd(&counts[dst[i]], 1);
}

__global__ __launch_bounds__(256) void scan_block_sums(const int* __restrict__ counts,
                                                       int* __restrict__ bsum, int N) {
    __shared__ int sm[256];
    int i = blockIdx.x * 256 + threadIdx.x;
    sm[threadIdx.x] = (i < N) ? counts[i] : 0;
    __syncthreads();
#pragma unroll
    for (int off = 128; off; off >>= 1) {
        if (threadIdx.x < off) sm[threadIdx.x] += sm[threadIdx.x + off];
        __syncthreads();
    }
    if (threadIdx.x == 0) bsum[blockIdx.x] = sm[0];
}

__global__ __launch_bounds__(256) void scan_top(const int* __restrict__ bsum,
                                                int* __restrict__ bsum_ex, int NB) {
    __shared__ int sm[256];
    int t = threadIdx.x;
    sm[t] = (t < NB) ? bsum[t] : 0;
    __syncthreads();
    for (int off = 1; off < 256; off <<= 1) {
        int v = (t >= off) ? sm[t - off] : 0;
        __syncthreads();
        sm[t] += v;
        __syncthreads();
    }
    if (t < NB) bsum_ex[t] = (t == 0) ? 0 : sm[t - 1];
}

__global__ __launch_bounds__(256) void scan_final(const int* __restrict__ counts,
                                                  const int* __restrict__ bsum_ex,
                                                  int* __restrict__ rowptr,
                                                  int* __restrict__ cursor, int N, int E) {
    __shared__ int sm[256];
    int t = threadIdx.x;
    int i = blockIdx.x * 256 + t;
    sm[t] = (i < N) ? counts[i] : 0;
    __syncthreads();
    for (int off = 1; off < 256; off <<= 1) {
        int v = (t >= off) ? sm[t - off] : 0;
        __syncthreads();
        sm[t] += v;
        __syncthreads();
    }
    int ex = bsum_ex[blockIdx.x] + ((t == 0) ? 0 : sm[t - 1]);
    if (i < N) { rowptr[i] = ex; cursor[i] = ex; }
    if (i == 0) rowptr[N] = E;
}

__global__ __launch_bounds__(256) void scatter_kernel(
    const int* __restrict__ src, const int* __restrict__ dst,
    const float* __restrict__ reward, int* __restrict__ cursor,
    int* __restrict__ esrc, float* __restrict__ erew, int E) {
    int i = blockIdx.x * 256 + threadIdx.x;
    if (i < E) {
        int d = dst[i];
        int pos = atomicAdd(&cursor[d], 1);
        esrc[pos] = src[i];
        erew[pos] = reward[i];
    }
}

// ---- fused per-node edge phase ----------------------------------------------
// One wave per dst node. Pass 1: lane covers j=lane*4..+3 (head = lane>>4);
// logits via 16-lane xor-shfl reduce; exp stored to ee (sorted order), denom
// accumulated in registers. Pass 2: lane = output dim o; weighted bf16 gather
// of h_src; coalesced out write with 0.25/denom and relu folded in.

__global__ __launch_bounds__(256) void node_fused(
    const ushort_t* __restrict__ fatt, const ushort_t* __restrict__ hsb,
    const int* __restrict__ rowptr, const int* __restrict__ esrc,
    const float* __restrict__ erew, const float* __restrict__ wsum,
    const float* __restrict__ attn, float* __restrict__ ee,
    float* __restrict__ out, int N) {
    int node = (int)((blockIdx.x * (size_t)blockDim.x + threadIdx.x) >> 6);
    int lane = threadIdx.x & 63;
    if (node >= N) return;

    int base = rowptr[node], end = rowptr[node + 1];
    int j0 = lane * 4;

    float4 ws = *(const float4*)(wsum + j0);
    float4 at = *(const float4*)(attn + j0);
    ushort4 njv = *(const ushort4*)(fatt + (size_t)node * 512 + 256 + j0);
    float nj0 = bf2f(njv.x), nj1 = bf2f(njv.y), nj2 = bf2f(njv.z), nj3 = bf2f(njv.w);

    float dsum = 0.f;
    for (int e = base; e < end; ++e) {
        int s = esrc[e];
        float r = erew[e];
        ushort4 ni = *(const ushort4*)(fatt + (size_t)s * 512 + j0);
        float x0 = bf2f(ni.x) + nj0 + r * ws.x;
        float x1 = bf2f(ni.y) + nj1 + r * ws.y;
        float x2 = bf2f(ni.z) + nj2 + r * ws.z;
        float x3 = bf2f(ni.w) + nj3 + r * ws.w;
        x0 = x0 > 0.f ? x0 : 0.2f * x0;
        x1 = x1 > 0.f ? x1 : 0.2f * x1;
        x2 = x2 > 0.f ? x2 : 0.2f * x2;
        x3 = x3 > 0.f ? x3 : 0.2f * x3;
        float acc = at.x * x0 + at.y * x1 + at.z * x2 + at.w * x3;
        acc += __shfl_xor(acc, 1, 64);
        acc += __shfl_xor(acc, 2, 64);
        acc += __shfl_xor(acc, 4, 64);
        acc += __shfl_xor(acc, 8, 64);
        float v = __expf(acc);
        if ((lane & 15) == 0) ee[(size_t)e * 4 + (lane >> 4)] = v;
        dsum += v;
    }

    // dsum on every lane = denom of head (lane>>4); gather all 4 per lane
    float inv0 = 0.25f / __shfl(dsum, 0, 64);
    float inv1 = 0.25f / __shfl(dsum, 16, 64);
    float inv2 = 0.25f / __shfl(dsum, 32, 64);
    float inv3 = 0.25f / __shfl(dsum, 48, 64);

    const int o = lane;
    float accv = 0.f;
    for (int e = base; e < end; ++e) {
        int s = esrc[e];
        float4 w = *(const float4*)(ee + (size_t)e * 4);
        const ushort_t* hs = hsb + (size_t)s * 256;
        accv += (w.x * inv0) * bf2f(hs[o]) + (w.y * inv1) * bf2f(hs[64 + o]) +
                (w.z * inv2) * bf2f(hs[128 + o]) + (w.w * inv3) * bf2f(hs[192 + o]);
    }
    out[(size_t)node * 64 + o] = fmaxf(accv, 0.f);
}

// ---- launch -----------------------------------------------------------------

extern "C" void kernel_launch(void* const* d_in, const int* in_sizes, int n_in,
                              void* d_out, int out_size, void* d_ws, size_t ws_size,
                              hipStream_t stream) {
    const float* nfeats = (const float*)d_in[0];
    const float* reward = (const float*)d_in[1];
    const int* src = (const int*)d_in[2];
    const int* dst = (const int*)d_in[3];
    const float* Wni = (const float*)d_in[4];
    const float* Wnj = (const float*)d_in[5];
    const float* Wfij = (const float*)d_in[6];
    const float* Wnode = (const float*)d_in[7];
    const float* bias = (const float*)d_in[8];
    const float* attn = (const float*)d_in[9];
    float* out = (float*)d_out;

    const int N = in_sizes[0] / 256;
    const int E = in_sizes[1];
    const int NB = (N + 255) / 256;  // must be <= 256 (N <= 65536)

    char* p = (char*)d_ws;
    auto alloc = [&](size_t bytes) { char* r = p; p += (bytes + 63) & ~63ull; return r; };
    float* ee = (float*)alloc((size_t)E * 4 * sizeof(float));
    float* wsum = (float*)alloc(256 * sizeof(float));
    float* erew = (float*)alloc((size_t)E * sizeof(float));
    int* counts = (int*)alloc((size_t)N * sizeof(int));
    int* bsum = (int*)alloc(256 * sizeof(int));
    int* bsum_ex = (int*)alloc(256 * sizeof(int));
    int* rowptr = (int*)alloc((size_t)(N + 1) * sizeof(int));
    int* cursor = (int*)alloc((size_t)N * sizeof(int));
    int* esrc = (int*)alloc((size_t)E * sizeof(int));
    ushort_t* fatt = (ushort_t*)alloc((size_t)N * 512 * sizeof(ushort_t));
    ushort_t* hsb = (ushort_t*)alloc((size_t)N * 256 * sizeof(ushort_t));
    ushort_t* Abf = (ushort_t*)alloc((size_t)N * 256 * sizeof(ushort_t));
    ushort_t* Bcat = (ushort_t*)alloc((size_t)256 * 768 * sizeof(ushort_t));

    hipMemsetAsync(counts, 0, (size_t)N * sizeof(int), stream);

    int total4 = N * 64;
    cast_nfeats<<<(total4 + 255) / 256, 256, 0, stream>>>(nfeats, Abf, total4);
    build_bcat<<<256, 768, 0, stream>>>(Wni, Wnj, Wnode, Bcat);
    wsum_kernel<<<1, 256, 0, stream>>>(Wfij, wsum);

    // counting sort by dst
    count_kernel<<<(E + 255) / 256, 256, 0, stream>>>(dst, counts, E);
    scan_block_sums<<<NB, 256, 0, stream>>>(counts, bsum, N);
    scan_top<<<1, 256, 0, stream>>>(bsum, bsum_ex, NB);
    scan_final<<<NB, 256, 0, stream>>>(counts, bsum_ex, rowptr, cursor, N, E);
    scatter_kernel<<<(E + 255) / 256, 256, 0, stream>>>(src, dst, reward, cursor,
                                                        esrc, erew, E);

    dim3 g1((N + 127) / 128, 12);
    gemm_mfma<<<g1, 256, 0, stream>>>(Abf, Bcat, bias, fatt, hsb, N);

    node_fused<<<(N + 3) / 4, 256, 0, stream>>>(fatt, hsb, rowptr, esrc, erew,
                                                wsum, attn, ee, out, N);
}

// Round 4
// 390.032 us; speedup vs baseline: 2.0267x; 1.2496x over previous
//
#include <hip/hip_runtime.h>

// EdgeGAT on MI355X — round 4: single-pass node kernel + dense tables + 128x128 GEMM.
//
//   c0: cast nfeats fp32 -> bf16 (Abf)
//   c1: build BcatT bf16 [768][256] (n-major = B^T) from [W_ni|W_nj|W_node]
//   k0: wsum[j] = sum_k W_fij[k,j]
//   k1: MFMA GEMM 128x128 tile: cols 0..255 (+bias) -> fni bf16 [N][256]
//       cols 256..511 -> fnj bf16 [N][256]; cols 512..767 -> hsb2 bf16 [N][64][4]
//   s*: counting sort by dst -> rowptr + epair (src,reward packed 8B)
//   k2: node_fused — per dst node (1 wave), SINGLE pass over edges:
//       logits+exp -> unnormalized per-head accumulation of h_src; divide by
//       denom at the end; coalesced out write with 0.25*mean + relu folded.

typedef unsigned short ushort_t;
typedef __attribute__((ext_vector_type(8))) unsigned short ushort8v;
typedef __attribute__((ext_vector_type(8))) short frag_t;     // 8 bf16 (4 VGPRs)
typedef __attribute__((ext_vector_type(4))) float f32x4;
typedef unsigned long long u64_t;

__device__ __forceinline__ ushort_t f2bf(float f) {
    unsigned u = __float_as_uint(f);
    unsigned r = u + 0x7fffu + ((u >> 16) & 1u);   // round-to-nearest-even
    return (ushort_t)(r >> 16);
}
__device__ __forceinline__ float bf2f(ushort_t v) {
    return __uint_as_float(((unsigned)v) << 16);
}

// ---- cast kernels -----------------------------------------------------------

__global__ __launch_bounds__(256) void cast_nfeats(const float* __restrict__ in,
                                                   ushort_t* __restrict__ out, int total4) {
    int i = blockIdx.x * 256 + threadIdx.x;
    if (i >= total4) return;
    float4 v = *(const float4*)(in + (size_t)i * 4);
    ushort4 o;
    o.x = f2bf(v.x); o.y = f2bf(v.y); o.z = f2bf(v.z); o.w = f2bf(v.w);
    *(ushort4*)(out + (size_t)i * 4) = o;
}

// grid=(256 k), block=(768 j): BcatT[j][k] (transposed, n-major)
__global__ __launch_bounds__(768) void build_bcat(const float* __restrict__ Wni,
                                                  const float* __restrict__ Wnj,
                                                  const float* __restrict__ Wnode,
                                                  ushort_t* __restrict__ BcatT) {
    int k = blockIdx.x;
    int j = threadIdx.x;
    int seg = j >> 8;
    const float* W = (seg == 0) ? Wni : (seg == 1) ? Wnj : Wnode;
    BcatT[(size_t)j * 256 + k] = f2bf(W[(size_t)k * 256 + (j & 255)]);
}

__global__ __launch_bounds__(256) void wsum_kernel(const float* __restrict__ Wfij,
                                                   float* __restrict__ wsum) {
    int j = threadIdx.x;
    float s = 0.f;
#pragma unroll
    for (int k = 0; k < 32; ++k) s += Wfij[k * 256 + j];
    wsum[j] = s;
}

// ---- MFMA GEMM 128x128 ------------------------------------------------------
// 4 waves as 2x2; each wave 4x4 frags of 16x16x32 bf16 (16 MFMA / K-step).
// A [N][256] bf16 row-major; B = BcatT [768][256] bf16 (n-major) so both
// stage contiguously along k. C/D layout: col=lane&15, row=quad*4+reg.

__global__ __launch_bounds__(256) void gemm_mfma(
    const ushort_t* __restrict__ A, const ushort_t* __restrict__ BT,
    const float* __restrict__ bias, ushort_t* __restrict__ fni,
    ushort_t* __restrict__ fnj, ushort_t* __restrict__ hsb2, int N) {
    __shared__ ushort_t As[128][40];   // 80B rows: conflict-free b128 frag reads
    __shared__ ushort_t Bs[128][40];

    const int tid = threadIdx.x;
    const int wave = tid >> 6, lane = tid & 63;
    const int quad = lane >> 4, l16 = lane & 15;
    const int wr = wave & 1, wc = wave >> 1;
    const int row0 = blockIdx.x * 128;
    const int col0 = blockIdx.y * 128;         // 0..640

    const int sr = tid >> 1;                    // 0..127 (row within tile)
    const int sk = (tid & 1) * 16;              // 0 or 16 (k offset)

    f32x4 acc[4][4] = {};

    for (int k0 = 0; k0 < 256; k0 += 32) {
        if (k0) __syncthreads();
        {
            int grow = row0 + sr;
            ushort8v v0 = {}, v1 = {};
            if (grow < N) {
                const ushort_t* p = A + (size_t)grow * 256 + k0 + sk;
                v0 = *(const ushort8v*)p;
                v1 = *(const ushort8v*)(p + 8);
            }
            *(ushort8v*)&As[sr][sk] = v0;
            *(ushort8v*)&As[sr][sk + 8] = v1;
        }
        {
            const ushort_t* p = BT + (size_t)(col0 + sr) * 256 + k0 + sk;
            ushort8v v0 = *(const ushort8v*)p;
            ushort8v v1 = *(const ushort8v*)(p + 8);
            *(ushort8v*)&Bs[sr][sk] = v0;
            *(ushort8v*)&Bs[sr][sk + 8] = v1;
        }
        __syncthreads();

        frag_t af[4], bfr[4];
#pragma unroll
        for (int i = 0; i < 4; ++i)
            af[i] = *(const frag_t*)&As[wr * 64 + i * 16 + l16][quad * 8];
#pragma unroll
        for (int j = 0; j < 4; ++j)
            bfr[j] = *(const frag_t*)&Bs[wc * 64 + j * 16 + l16][quad * 8];

#pragma unroll
        for (int i = 0; i < 4; ++i)
#pragma unroll
            for (int j = 0; j < 4; ++j)
                acc[i][j] = __builtin_amdgcn_mfma_f32_16x16x32_bf16(af[i], bfr[j], acc[i][j], 0, 0, 0);
    }

#pragma unroll
    for (int i = 0; i < 4; ++i) {
#pragma unroll
        for (int j = 0; j < 4; ++j) {
#pragma unroll
            for (int r = 0; r < 4; ++r) {
                int row = row0 + wr * 64 + i * 16 + quad * 4 + r;
                if (row >= N) continue;
                int col = col0 + wc * 64 + j * 16 + l16;
                float v = acc[i][j][r];
                if (col < 256) {
                    fni[(size_t)row * 256 + col] = f2bf(v + bias[col]);
                } else if (col < 512) {
                    fnj[(size_t)row * 256 + (col - 256)] = f2bf(v);
                } else {
                    int c2 = col - 512;           // h = c2>>6, o = c2&63
                    hsb2[(size_t)row * 256 + (c2 & 63) * 4 + (c2 >> 6)] = f2bf(v);
                }
            }
        }
    }
}

// ---- counting sort by dst ---------------------------------------------------

__global__ __launch_bounds__(256) void count_kernel(const int* __restrict__ dst,
                                                    int* __restrict__ counts, int E) {
    int i = blockIdx.x * 256 + threadIdx.x;
    if (i < E) atomicAdd(&counts[dst[i]], 1);
}

__global__ __launch_bounds__(256) void scan_block_sums(const int* __restrict__ counts,
                                                       int* __restrict__ bsum, int N) {
    __shared__ int sm[256];
    int i = blockIdx.x * 256 + threadIdx.x;
    sm[threadIdx.x] = (i < N) ? counts[i] : 0;
    __syncthreads();
#pragma unroll
    for (int off = 128; off; off >>= 1) {
        if (threadIdx.x < off) sm[threadIdx.x] += sm[threadIdx.x + off];
        __syncthreads();
    }
    if (threadIdx.x == 0) bsum[blockIdx.x] = sm[0];
}

__global__ __launch_bounds__(256) void scan_top(const int* __restrict__ bsum,
                                                int* __restrict__ bsum_ex, int NB) {
    __shared__ int sm[256];
    int t = threadIdx.x;
    sm[t] = (t < NB) ? bsum[t] : 0;
    __syncthreads();
    for (int off = 1; off < 256; off <<= 1) {
        int v = (t >= off) ? sm[t - off] : 0;
        __syncthreads();
        sm[t] += v;
        __syncthreads();
    }
    if (t < NB) bsum_ex[t] = (t == 0) ? 0 : sm[t - 1];
}

__global__ __launch_bounds__(256) void scan_final(const int* __restrict__ counts,
                                                  const int* __restrict__ bsum_ex,
                                                  int* __restrict__ rowptr,
                                                  int* __restrict__ cursor, int N, int E) {
    __shared__ int sm[256];
    int t = threadIdx.x;
    int i = blockIdx.x * 256 + t;
    sm[t] = (i < N) ? counts[i] : 0;
    __syncthreads();
    for (int off = 1; off < 256; off <<= 1) {
        int v = (t >= off) ? sm[t - off] : 0;
        __syncthreads();
        sm[t] += v;
        __syncthreads();
    }
    int ex = bsum_ex[blockIdx.x] + ((t == 0) ? 0 : sm[t - 1]);
    if (i < N) { rowptr[i] = ex; cursor[i] = ex; }
    if (i == 0) rowptr[N] = E;
}

__global__ __launch_bounds__(256) void scatter_kernel(
    const int* __restrict__ src, const int* __restrict__ dst,
    const float* __restrict__ reward, int* __restrict__ cursor,
    u64_t* __restrict__ epair, int E) {
    int i = blockIdx.x * 256 + threadIdx.x;
    if (i < E) {
        int d = dst[i];
        int pos = atomicAdd(&cursor[d], 1);
        epair[pos] = ((u64_t)__float_as_uint(reward[i]) << 32) | (unsigned)src[i];
    }
}

// ---- fused per-node edge phase (single pass) --------------------------------
// One wave per dst node. Lane duals: logit dims j = lane*4..+3 (head lane>>4)
// AND output dim o = lane. Per edge: gather fni[s] (ushort4) + hsb2[s][o][0:4]
// (ushort4, independent loads), logit -> exp -> broadcast 4 head weights ->
// unnormalized accumulate. Normalize + 0.25*mean + relu once at the end.

__global__ __launch_bounds__(256) void node_fused(
    const ushort_t* __restrict__ fni, const ushort_t* __restrict__ fnj,
    const ushort_t* __restrict__ hsb2, const int* __restrict__ rowptr,
    const u64_t* __restrict__ epair, const float* __restrict__ wsum,
    const float* __restrict__ attn, float* __restrict__ out, int N) {
    int node = (int)((blockIdx.x * (size_t)blockDim.x + threadIdx.x) >> 6);
    int lane = threadIdx.x & 63;
    if (node >= N) return;

    int base = rowptr[node], end = rowptr[node + 1];
    int j0 = lane * 4;

    float4 ws = *(const float4*)(wsum + j0);
    float4 at = *(const float4*)(attn + j0);
    ushort4 njv = *(const ushort4*)(fnj + (size_t)node * 256 + j0);
    float nj0 = bf2f(njv.x), nj1 = bf2f(njv.y), nj2 = bf2f(njv.z), nj3 = bf2f(njv.w);

    float a0 = 0.f, a1 = 0.f, a2 = 0.f, a3 = 0.f, dsum = 0.f;

    u64_t pr = (base < end) ? epair[base] : 0;
    for (int e = base; e < end; ++e) {
        u64_t cur = pr;
        if (e + 1 < end) pr = epair[e + 1];    // prefetch: breaks serial chain
        int s = (int)(unsigned)cur;
        float r = __uint_as_float((unsigned)(cur >> 32));

        ushort4 ni = *(const ushort4*)(fni + (size_t)s * 256 + j0);
        ushort4 hv = *(const ushort4*)(hsb2 + (size_t)s * 256 + lane * 4);

        float x0 = bf2f(ni.x) + nj0 + r * ws.x;
        float x1 = bf2f(ni.y) + nj1 + r * ws.y;
        float x2 = bf2f(ni.z) + nj2 + r * ws.z;
        float x3 = bf2f(ni.w) + nj3 + r * ws.w;
        x0 = x0 > 0.f ? x0 : 0.2f * x0;
        x1 = x1 > 0.f ? x1 : 0.2f * x1;
        x2 = x2 > 0.f ? x2 : 0.2f * x2;
        x3 = x3 > 0.f ? x3 : 0.2f * x3;
        float acc = at.x * x0 + at.y * x1 + at.z * x2 + at.w * x3;
        acc += __shfl_xor(acc, 1, 64);
        acc += __shfl_xor(acc, 2, 64);
        acc += __shfl_xor(acc, 4, 64);
        acc += __shfl_xor(acc, 8, 64);
        float eh = __expf(acc);                // per-16-group head logit exp
        dsum += eh;

        float e0 = __shfl(eh, 0, 64);
        float e1 = __shfl(eh, 16, 64);
        float e2 = __shfl(eh, 32, 64);
        float e3 = __shfl(eh, 48, 64);
        a0 += e0 * bf2f(hv.x);
        a1 += e1 * bf2f(hv.y);
        a2 += e2 * bf2f(hv.z);
        a3 += e3 * bf2f(hv.w);
    }

    float d0 = __shfl(dsum, 0, 64);
    float d1 = __shfl(dsum, 16, 64);
    float d2 = __shfl(dsum, 32, 64);
    float d3 = __shfl(dsum, 48, 64);
    float v = 0.25f * (__fdividef(a0, d0) + __fdividef(a1, d1) +
                       __fdividef(a2, d2) + __fdividef(a3, d3));
    out[(size_t)node * 64 + lane] = fmaxf(v, 0.f);
}

// ---- launch -----------------------------------------------------------------

extern "C" void kernel_launch(void* const* d_in, const int* in_sizes, int n_in,
                              void* d_out, int out_size, void* d_ws, size_t ws_size,
                              hipStream_t stream) {
    const float* nfeats = (const float*)d_in[0];
    const float* reward = (const float*)d_in[1];
    const int* src = (const int*)d_in[2];
    const int* dst = (const int*)d_in[3];
    const float* Wni = (const float*)d_in[4];
    const float* Wnj = (const float*)d_in[5];
    const float* Wfij = (const float*)d_in[6];
    const float* Wnode = (const float*)d_in[7];
    const float* bias = (const float*)d_in[8];
    const float* attn = (const float*)d_in[9];
    float* out = (float*)d_out;

    const int N = in_sizes[0] / 256;
    const int E = in_sizes[1];
    const int NB = (N + 255) / 256;  // <= 256 required (N <= 65536)

    char* p = (char*)d_ws;
    auto alloc = [&](size_t bytes) { char* r = p; p += (bytes + 63) & ~63ull; return r; };
    u64_t* epair = (u64_t*)alloc((size_t)E * sizeof(u64_t));
    float* wsum = (float*)alloc(256 * sizeof(float));
    int* counts = (int*)alloc((size_t)N * sizeof(int));
    int* bsum = (int*)alloc(256 * sizeof(int));
    int* bsum_ex = (int*)alloc(256 * sizeof(int));
    int* rowptr = (int*)alloc((size_t)(N + 1) * sizeof(int));
    int* cursor = (int*)alloc((size_t)N * sizeof(int));
    ushort_t* fni = (ushort_t*)alloc((size_t)N * 256 * sizeof(ushort_t));
    ushort_t* fnj = (ushort_t*)alloc((size_t)N * 256 * sizeof(ushort_t));
    ushort_t* hsb2 = (ushort_t*)alloc((size_t)N * 256 * sizeof(ushort_t));
    ushort_t* Abf = (ushort_t*)alloc((size_t)N * 256 * sizeof(ushort_t));
    ushort_t* BcatT = (ushort_t*)alloc((size_t)768 * 256 * sizeof(ushort_t));

    hipMemsetAsync(counts, 0, (size_t)N * sizeof(int), stream);

    int total4 = N * 64;
    cast_nfeats<<<(total4 + 255) / 256, 256, 0, stream>>>(nfeats, Abf, total4);
    build_bcat<<<256, 768, 0, stream>>>(Wni, Wnj, Wnode, BcatT);
    wsum_kernel<<<1, 256, 0, stream>>>(Wfij, wsum);

    count_kernel<<<(E + 255) / 256, 256, 0, stream>>>(dst, counts, E);
    scan_block_sums<<<NB, 256, 0, stream>>>(counts, bsum, N);
    scan_top<<<1, 256, 0, stream>>>(bsum, bsum_ex, NB);
    scan_final<<<NB, 256, 0, stream>>>(counts, bsum_ex, rowptr, cursor, N, E);
    scatter_kernel<<<(E + 255) / 256, 256, 0, stream>>>(src, dst, reward, cursor,
                                                        epair, E);

    dim3 g1((N + 127) / 128, 6);
    gemm_mfma<<<g1, 256, 0, stream>>>(Abf, BcatT, bias, fni, fnj, hsb2, N);

    node_fused<<<(N + 3) / 4, 256, 0, stream>>>(fni, fnj, hsb2, rowptr, epair,
                                                wsum, attn, out, N);
}

// Round 5
// 377.219 us; speedup vs baseline: 2.0956x; 1.0340x over previous
//
#include <hip/hip_runtime.h>

// EdgeGAT on MI355X — round 5: global_load_lds GEMM + fused prep + pipelined node kernel.
//
//   prep: cast nfeats->bf16 | build BcatT bf16 [768][256] | wsum | dst histogram
//   scan1/scan2/scan3: rowptr exclusive scan (+cursor)
//   scatter: edges -> epair (src,reward) packed 8B, dst-sorted
//   gemm: 128x128 tile, BK=32, global_load_lds(16B) staging, 16x16x32 bf16 MFMA
//         cols 0..255 (+bias) -> fnih[row][0:256]; 256..511 -> fnj[row][0:256];
//         512..767 -> fnih[row][256+ (o*4+h)]  (o-major, heads packed)
//   node_fused: per dst node (1 wave), single pass, gathers pipelined 1 edge ahead.

typedef unsigned short ushort_t;
typedef __attribute__((ext_vector_type(8))) short frag_t;     // 8 bf16 (4 VGPRs)
typedef __attribute__((ext_vector_type(4))) float f32x4;
typedef unsigned long long u64_t;

__device__ __forceinline__ ushort_t f2bf(float f) {
    unsigned u = __float_as_uint(f);
    unsigned r = u + 0x7fffu + ((u >> 16) & 1u);   // round-to-nearest-even
    return (ushort_t)(r >> 16);
}
__device__ __forceinline__ float bf2f(ushort_t v) {
    return __uint_as_float(((unsigned)v) << 16);
}

// async 16B global->LDS (CK idiom: truncate generic LDS ptr to AS3 offset)
__device__ __forceinline__ void async_load16(const void* g, void* l) {
    __builtin_amdgcn_global_load_lds(
        (const __attribute__((address_space(1))) unsigned int*)g,
        (__attribute__((address_space(3))) unsigned int*)(unsigned int)(uintptr_t)l,
        16, 0, 0);
}

// ---- fused prep: cast | bcatT | wsum | count --------------------------------
__global__ __launch_bounds__(256) void prep_kernel(
    const float* __restrict__ nfeats, const float* __restrict__ Wni,
    const float* __restrict__ Wnj, const float* __restrict__ Wnode,
    const float* __restrict__ Wfij, const int* __restrict__ dst,
    ushort_t* __restrict__ Abf, ushort_t* __restrict__ BcatT,
    float* __restrict__ wsum, int* __restrict__ counts,
    int castB, int countB, int E) {
    int b = blockIdx.x;
    int t = threadIdx.x;
    if (b < castB) {                       // cast nfeats: 4 floats/thread
        int i = b * 256 + t;
        float4 v = *(const float4*)(nfeats + (size_t)i * 4);
        ushort4 o;
        o.x = f2bf(v.x); o.y = f2bf(v.y); o.z = f2bf(v.z); o.w = f2bf(v.w);
        *(ushort4*)(Abf + (size_t)i * 4) = o;
    } else if (b < castB + 768) {          // BcatT[j][k], j = block, k = thread
        int j = b - castB;
        int seg = j >> 8;
        const float* W = (seg == 0) ? Wni : (seg == 1) ? Wnj : Wnode;
        BcatT[(size_t)j * 256 + t] = f2bf(W[(size_t)t * 256 + (j & 255)]);
    } else if (b < castB + 768 + countB) { // dst histogram
        int i = (b - castB - 768) * 256 + t;
        if (i < E) atomicAdd(&counts[dst[i]], 1);
    } else {                               // wsum
        float s = 0.f;
#pragma unroll
        for (int k = 0; k < 32; ++k) s += Wfij[k * 256 + t];
        wsum[t] = s;
    }
}

// ---- MFMA GEMM 128x128, global_load_lds staging -----------------------------
__global__ __launch_bounds__(256) void gemm_mfma(
    const ushort_t* __restrict__ A, const ushort_t* __restrict__ BT,
    const float* __restrict__ bias, ushort_t* __restrict__ fnih,
    ushort_t* __restrict__ fnj, int N) {
    __shared__ ushort_t As[128][32];   // unpadded: global_load_lds dest is lane-linear
    __shared__ ushort_t Bs[128][32];

    const int tid = threadIdx.x;
    const int wave = tid >> 6, lane = tid & 63;
    const int quad = lane >> 4, l16 = lane & 15;
    const int wr = wave & 1, wc = wave >> 1;
    const int row0 = blockIdx.x * 128;
    const int col0 = blockIdx.y * 128;         // 0..640
    const int Nm1 = N - 1;

    // staging: issue j covers 16 rows x 32 k (1 KB); lane -> row=lane>>2, k=(lane&3)*8
    const int lrow = lane >> 2;
    const int lk = (lane & 3) * 8;

    f32x4 acc[4][4] = {};

    for (int k0 = 0; k0 < 256; k0 += 32) {
        if (k0) __syncthreads();
#pragma unroll
        for (int j = 0; j < 2; ++j) {
            int r = wave * 32 + j * 16 + lrow;
            int grow = row0 + r; if (grow > Nm1) grow = Nm1;   // clamp, discarded later
            async_load16(A + (size_t)grow * 256 + k0 + lk, &As[wave * 32 + j * 16][0]);
        }
#pragma unroll
        for (int j = 0; j < 2; ++j) {
            int r = wave * 32 + j * 16 + lrow;
            async_load16(BT + (size_t)(col0 + r) * 256 + k0 + lk, &Bs[wave * 32 + j * 16][0]);
        }
        __syncthreads();

        frag_t af[4], bfr[4];
#pragma unroll
        for (int i = 0; i < 4; ++i)
            af[i] = *(const frag_t*)&As[wr * 64 + i * 16 + l16][quad * 8];
#pragma unroll
        for (int j = 0; j < 4; ++j)
            bfr[j] = *(const frag_t*)&Bs[wc * 64 + j * 16 + l16][quad * 8];

#pragma unroll
        for (int i = 0; i < 4; ++i)
#pragma unroll
            for (int j = 0; j < 4; ++j)
                acc[i][j] = __builtin_amdgcn_mfma_f32_16x16x32_bf16(af[i], bfr[j], acc[i][j], 0, 0, 0);
    }

#pragma unroll
    for (int i = 0; i < 4; ++i) {
#pragma unroll
        for (int j = 0; j < 4; ++j) {
#pragma unroll
            for (int r = 0; r < 4; ++r) {
                int row = row0 + wr * 64 + i * 16 + quad * 4 + r;
                if (row >= N) continue;
                int col = col0 + wc * 64 + j * 16 + l16;
                float v = acc[i][j][r];
                if (col < 256) {
                    fnih[(size_t)row * 512 + col] = f2bf(v + bias[col]);
                } else if (col < 512) {
                    fnj[(size_t)row * 256 + (col - 256)] = f2bf(v);
                } else {
                    int c2 = col - 512;   // h = c2>>6, o = c2&63 -> o-major
                    fnih[(size_t)row * 512 + 256 + (c2 & 63) * 4 + (c2 >> 6)] = f2bf(v);
                }
            }
        }
    }
}

// ---- scans ------------------------------------------------------------------

__global__ __launch_bounds__(256) void scan_block_sums(const int* __restrict__ counts,
                                                       int* __restrict__ bsum, int N) {
    __shared__ int sm[256];
    int i = blockIdx.x * 256 + threadIdx.x;
    sm[threadIdx.x] = (i < N) ? counts[i] : 0;
    __syncthreads();
#pragma unroll
    for (int off = 128; off; off >>= 1) {
        if (threadIdx.x < off) sm[threadIdx.x] += sm[threadIdx.x + off];
        __syncthreads();
    }
    if (threadIdx.x == 0) bsum[blockIdx.x] = sm[0];
}

__global__ __launch_bounds__(256) void scan_top(const int* __restrict__ bsum,
                                                int* __restrict__ bsum_ex, int NB) {
    __shared__ int sm[256];
    int t = threadIdx.x;
    sm[t] = (t < NB) ? bsum[t] : 0;
    __syncthreads();
    for (int off = 1; off < 256; off <<= 1) {
        int v = (t >= off) ? sm[t - off] : 0;
        __syncthreads();
        sm[t] += v;
        __syncthreads();
    }
    if (t < NB) bsum_ex[t] = (t == 0) ? 0 : sm[t - 1];
}

__global__ __launch_bounds__(256) void scan_final(const int* __restrict__ counts,
                                                  const int* __restrict__ bsum_ex,
                                                  int* __restrict__ rowptr,
                                                  int* __restrict__ cursor, int N, int E) {
    __shared__ int sm[256];
    int t = threadIdx.x;
    int i = blockIdx.x * 256 + t;
    sm[t] = (i < N) ? counts[i] : 0;
    __syncthreads();
    for (int off = 1; off < 256; off <<= 1) {
        int v = (t >= off) ? sm[t - off] : 0;
        __syncthreads();
        sm[t] += v;
        __syncthreads();
    }
    int ex = bsum_ex[blockIdx.x] + ((t == 0) ? 0 : sm[t - 1]);
    if (i < N) { rowptr[i] = ex; cursor[i] = ex; }
    if (i == 0) rowptr[N] = E;
}

__global__ __launch_bounds__(256) void scatter_kernel(
    const int* __restrict__ src, const int* __restrict__ dst,
    const float* __restrict__ reward, int* __restrict__ cursor,
    u64_t* __restrict__ epair, int E) {
    int i = blockIdx.x * 256 + threadIdx.x;
    if (i < E) {
        int d = dst[i];
        int pos = atomicAdd(&cursor[d], 1);
        epair[pos] = ((u64_t)__float_as_uint(reward[i]) << 32) | (unsigned)src[i];
    }
}

// ---- fused per-node edge phase (single pass, pipelined gathers) -------------

__global__ __launch_bounds__(256) void node_fused(
    const ushort_t* __restrict__ fnih, const ushort_t* __restrict__ fnj,
    const int* __restrict__ rowptr, const u64_t* __restrict__ epair,
    const float* __restrict__ wsum, const float* __restrict__ attn,
    float* __restrict__ out, int N) {
    int node = (int)((blockIdx.x * (size_t)blockDim.x + threadIdx.x) >> 6);
    int lane = threadIdx.x & 63;
    if (node >= N) return;

    int base = rowptr[node], end = rowptr[node + 1];
    int j0 = lane * 4;
    if (base >= end) { out[(size_t)node * 64 + lane] = 0.f; return; }

    float4 ws = *(const float4*)(wsum + j0);
    float4 at = *(const float4*)(attn + j0);
    ushort4 njv = *(const ushort4*)(fnj + (size_t)node * 256 + j0);
    float nj0 = bf2f(njv.x), nj1 = bf2f(njv.y), nj2 = bf2f(njv.z), nj3 = bf2f(njv.w);

    float a0 = 0.f, a1 = 0.f, a2 = 0.f, a3 = 0.f, dsum = 0.f;

    u64_t p0 = epair[base];
    u64_t p1 = (base + 1 < end) ? epair[base + 1] : 0;
    const ushort_t* fp = fnih + (size_t)(unsigned)p0 * 512 + j0;
    ushort4 ni = *(const ushort4*)fp;
    ushort4 hv = *(const ushort4*)(fp + 256);

    for (int e = base; e < end; ++e) {
        // prefetch next edge's gathers (overlaps the math below)
        u64_t pn = (e + 2 < end) ? epair[e + 2] : 0;
        ushort4 ni_n = ni, hv_n = hv;
        if (e + 1 < end) {
            const ushort_t* fq = fnih + (size_t)(unsigned)p1 * 512 + j0;
            ni_n = *(const ushort4*)fq;
            hv_n = *(const ushort4*)(fq + 256);
        }

        float r = __uint_as_float((unsigned)(p0 >> 32));
        float x0 = bf2f(ni.x) + nj0 + r * ws.x;
        float x1 = bf2f(ni.y) + nj1 + r * ws.y;
        float x2 = bf2f(ni.z) + nj2 + r * ws.z;
        float x3 = bf2f(ni.w) + nj3 + r * ws.w;
        x0 = x0 > 0.f ? x0 : 0.2f * x0;
        x1 = x1 > 0.f ? x1 : 0.2f * x1;
        x2 = x2 > 0.f ? x2 : 0.2f * x2;
        x3 = x3 > 0.f ? x3 : 0.2f * x3;
        float acc = at.x * x0 + at.y * x1 + at.z * x2 + at.w * x3;
        acc += __shfl_xor(acc, 1, 64);
        acc += __shfl_xor(acc, 2, 64);
        acc += __shfl_xor(acc, 4, 64);
        acc += __shfl_xor(acc, 8, 64);
        float eh = __expf(acc);
        dsum += eh;

        float e0 = __shfl(eh, 0, 64);
        float e1 = __shfl(eh, 16, 64);
        float e2 = __shfl(eh, 32, 64);
        float e3 = __shfl(eh, 48, 64);
        a0 += e0 * bf2f(hv.x);
        a1 += e1 * bf2f(hv.y);
        a2 += e2 * bf2f(hv.z);
        a3 += e3 * bf2f(hv.w);

        p0 = p1; p1 = pn; ni = ni_n; hv = hv_n;
    }

    float d0 = __shfl(dsum, 0, 64);
    float d1 = __shfl(dsum, 16, 64);
    float d2 = __shfl(dsum, 32, 64);
    float d3 = __shfl(dsum, 48, 64);
    float v = 0.25f * (__fdividef(a0, d0) + __fdividef(a1, d1) +
                       __fdividef(a2, d2) + __fdividef(a3, d3));
    out[(size_t)node * 64 + lane] = fmaxf(v, 0.f);
}

// ---- launch -----------------------------------------------------------------

extern "C" void kernel_launch(void* const* d_in, const int* in_sizes, int n_in,
                              void* d_out, int out_size, void* d_ws, size_t ws_size,
                              hipStream_t stream) {
    const float* nfeats = (const float*)d_in[0];
    const float* reward = (const float*)d_in[1];
    const int* src = (const int*)d_in[2];
    const int* dst = (const int*)d_in[3];
    const float* Wni = (const float*)d_in[4];
    const float* Wnj = (const float*)d_in[5];
    const float* Wfij = (const float*)d_in[6];
    const float* Wnode = (const float*)d_in[7];
    const float* bias = (const float*)d_in[8];
    const float* attn = (const float*)d_in[9];
    float* out = (float*)d_out;

    const int N = in_sizes[0] / 256;
    const int E = in_sizes[1];
    const int NB = (N + 255) / 256;       // <= 256 (N <= 65536)
    const int castB = (N * 64 + 255) / 256;
    const int countB = (E + 255) / 256;

    char* p = (char*)d_ws;
    auto alloc = [&](size_t bytes) { char* r = p; p += (bytes + 63) & ~63ull; return r; };
    u64_t* epair = (u64_t*)alloc((size_t)E * sizeof(u64_t));
    float* wsum = (float*)alloc(256 * sizeof(float));
    int* counts = (int*)alloc((size_t)N * sizeof(int));
    int* bsum = (int*)alloc(256 * sizeof(int));
    int* bsum_ex = (int*)alloc(256 * sizeof(int));
    int* rowptr = (int*)alloc((size_t)(N + 1) * sizeof(int));
    int* cursor = (int*)alloc((size_t)N * sizeof(int));
    ushort_t* fnih = (ushort_t*)alloc((size_t)N * 512 * sizeof(ushort_t));
    ushort_t* fnj = (ushort_t*)alloc((size_t)N * 256 * sizeof(ushort_t));
    ushort_t* Abf = (ushort_t*)alloc((size_t)N * 256 * sizeof(ushort_t));
    ushort_t* BcatT = (ushort_t*)alloc((size_t)768 * 256 * sizeof(ushort_t));

    hipMemsetAsync(counts, 0, (size_t)N * sizeof(int), stream);

    prep_kernel<<<castB + 768 + countB + 1, 256, 0, stream>>>(
        nfeats, Wni, Wnj, Wnode, Wfij, dst, Abf, BcatT, wsum, counts,
        castB, countB, E);

    scan_block_sums<<<NB, 256, 0, stream>>>(counts, bsum, N);
    scan_top<<<1, 256, 0, stream>>>(bsum, bsum_ex, NB);
    scan_final<<<NB, 256, 0, stream>>>(counts, bsum_ex, rowptr, cursor, N, E);
    scatter_kernel<<<countB, 256, 0, stream>>>(src, dst, reward, cursor, epair, E);

    dim3 g1((N + 127) / 128, 6);
    gemm_mfma<<<g1, 256, 0, stream>>>(Abf, BcatT, bias, fnih, fnj, N);

    node_fused<<<(N + 3) / 4, 256, 0, stream>>>(fnih, fnj, rowptr, epair,
                                                wsum, attn, out, N);
}